// Round 5
// baseline (1260.491 us; speedup 1.0000x reference)
//
#include <hip/hip_runtime.h>
#include <math.h>

#define N_NODES 50000
#define N_EDGES 1600000
#define IN_CH 32
#define HID 64

// ---------------- workspace layout (float/int element offsets into d_ws)
// Counting sort with 8 sub-buckets per node (bucket = e&7) to cut atomic
// contention ~8x. Counter arrays are scanned IN PLACE (counts -> offsets),
// then scatter bumps them back to end-offsets; deg/gather derive each node's
// range as [node==0 ? 0 : cur[node*8-1], cur[node*8+7]].
#define WS_RDEG_OUT  0          // 50000 f  (1/deg_out, written by deg_kernel dir 1)
#define WS_RDEG_IN   50000      // 50000 f  (1/deg_in,  written by deg_kernel dir 0)
#define WS_CUR_COL   100000     // 400000 i (per-node x8 sub-bucket counters, col dir)
#define WS_CUR_ROW   500000     // 400000 i (row dir)
#define WS_PAIR_COL  900000     // 3200000 i : int2 (src=row, w_bits), col-sorted
#define WS_PAIR_ROW  4100000    // 3200000 i : int2 (src=col, w_bits), row-sorted
#define WS_TXO       7300000    // 1600000 f (50000 x 32)
#define WS_TXI       900000     // 1600000 f -- ALIASES pair_col (dead before gather dir 1)
#define WS_HIGH      8900000    // 35.6 MB high-water ( < proven 40 MB budget)

__global__ void zero_kernel(float4* __restrict__ p, int n4) {
    int i = blockIdx.x * blockDim.x + threadIdx.x;
    int stride = gridDim.x * blockDim.x;
    for (; i < n4; i += stride) p[i] = make_float4(0.f, 0.f, 0.f, 0.f);
}

// sub-bucket counts only: 2 int atomics / edge (no float degree atomics)
__global__ void count_kernel(const int* __restrict__ ei,
                             int* __restrict__ cur_col, int* __restrict__ cur_row) {
    int e = blockIdx.x * blockDim.x + threadIdx.x;
    if (e >= N_EDGES) return;
    int r = ei[e];
    int c = ei[N_EDGES + e];
    int b = e & 7;
    atomicAdd(&cur_col[c * 8 + b], 1);
    atomicAdd(&cur_row[r * 8 + b], 1);
}

// In-place exclusive scan of 400000 sub-bucket counts (one block per array).
__global__ __launch_bounds__(1024) void scan_kernel(int* __restrict__ ws_i) {
    const int n = 8 * N_NODES;           // 400000
    const int T = 1024, CH = (n + T - 1) / T;  // 391
    __shared__ int s[1024];
    int* cnt = ws_i + (blockIdx.x == 0 ? WS_CUR_COL : WS_CUR_ROW);

    int t = threadIdx.x;
    int beg = t * CH, end = min(beg + CH, n);
    int part = 0;
    for (int i = beg; i < end; ++i) part += cnt[i];
    s[t] = part;
    __syncthreads();
    for (int off = 1; off < T; off <<= 1) {
        int v = (t >= off) ? s[t - off] : 0;
        __syncthreads();
        s[t] += v;
        __syncthreads();
    }
    int run = s[t] - part;  // exclusive prefix
    for (int i = beg; i < end; ++i) {
        int c = cnt[i];
        cnt[i] = run;
        run += c;
    }
}

// bucket-sort edges by destination: one packed int2 (src, raw w) per edge per dir
__global__ void scatter_kernel(const int* __restrict__ ei, const float* __restrict__ ew,
                               int* __restrict__ cur_col, int* __restrict__ cur_row,
                               int2* __restrict__ pair_col, int2* __restrict__ pair_row) {
    int e = blockIdx.x * blockDim.x + threadIdx.x;
    if (e >= N_EDGES) return;
    int r = ei[e];
    int c = ei[N_EDGES + e];
    int wb = __float_as_int(ew[e]);
    int b = e & 7;
    int p = atomicAdd(&cur_col[c * 8 + b], 1);
    pair_col[p] = make_int2(r, wb);
    int q = atomicAdd(&cur_row[r * 8 + b], 1);
    pair_row[q] = make_int2(c, wb);
}

#define GROUPS_PER_BLOCK 32
#define BLOCKS_PER_DIR ((N_NODES + GROUPS_PER_BLOCK - 1) / GROUPS_PER_BLOCK)  // 1563

// per-node degree = sum of w over its (contiguous) sorted list; write reciprocal.
// dir 0: col lists -> rdeg_in ; dir 1: row lists -> rdeg_out. 8 lanes per node.
__global__ __launch_bounds__(256) void deg_kernel(const int* __restrict__ ws_i,
                                                  float* __restrict__ ws_f) {
    int bidx = blockIdx.x;
    int dir = (bidx >= BLOCKS_PER_DIR) ? 1 : 0;
    int node = (bidx - dir * BLOCKS_PER_DIR) * GROUPS_PER_BLOCK + (threadIdx.x >> 3);
    if (node >= N_NODES) return;
    int lane = threadIdx.x & 7;
    const int* cur = ws_i + (dir == 0 ? WS_CUR_COL : WS_CUR_ROW);
    const int2* pair = (const int2*)(ws_i + (dir == 0 ? WS_PAIR_COL : WS_PAIR_ROW));
    float* rdeg = ws_f + (dir == 0 ? WS_RDEG_IN : WS_RDEG_OUT);

    int start = (node == 0) ? 0 : cur[node * 8 - 1];
    int end = cur[node * 8 + 7];
    float s = 0.f;
    for (int p = start + lane; p < end; p += 8) s += __int_as_float(pair[p].y);
    s += __shfl_down(s, 4, 8);
    s += __shfl_down(s, 2, 8);
    s += __shfl_down(s, 1, 8);
    if (lane == 0) rdeg[node] = (s != 0.f) ? (1.f / s) : 0.f;
}

// register-accumulating gather: 8 lanes per node, one float4 of channels each.
// coef = w * rdeg[src] (rdeg: 200 KB L2-resident table, broadcast across lanes).
__global__ __launch_bounds__(256) void gather_kernel(
    const float4* __restrict__ x4, const int* __restrict__ cur,
    const int2* __restrict__ pair, const float* __restrict__ rdeg,
    float4* __restrict__ outp) {
    int node = blockIdx.x * GROUPS_PER_BLOCK + (threadIdx.x >> 3);
    if (node >= N_NODES) return;
    int lane = threadIdx.x & 7;

    int p = (node == 0) ? 0 : cur[node * 8 - 1];
    int end = cur[node * 8 + 7];
    float4 acc = make_float4(0.f, 0.f, 0.f, 0.f);
    for (; p + 1 < end; p += 2) {
        int2 e0 = pair[p], e1 = pair[p + 1];
        float c0 = __int_as_float(e0.y) * rdeg[e0.x];
        float c1 = __int_as_float(e1.y) * rdeg[e1.x];
        float4 a = x4[e0.x * 8 + lane];
        float4 bb = x4[e1.x * 8 + lane];
        acc.x += c0 * a.x + c1 * bb.x;
        acc.y += c0 * a.y + c1 * bb.y;
        acc.z += c0 * a.z + c1 * bb.z;
        acc.w += c0 * a.w + c1 * bb.w;
    }
    if (p < end) {
        int2 e0 = pair[p];
        float c0 = __int_as_float(e0.y) * rdeg[e0.x];
        float4 a = x4[e0.x * 8 + lane];
        acc.x += c0 * a.x;
        acc.y += c0 * a.y;
        acc.z += c0 * a.z;
        acc.w += c0 * a.w;
    }
    outp[node * 8 + lane] = acc;
}

// Fused dense epilogue (unchanged from round 4 -- profiled off the top-5):
// weights transposed in LDS [o][k] stride 100, 16-node register batch per wave.
#define DN_GROUP 64
#define DN_BLOCKS ((N_NODES + DN_GROUP - 1) / DN_GROUP)  // 782
#define WT_STRIDE 100
__global__ __launch_bounds__(256) void dense_kernel(
    const float4* __restrict__ x4,
    const float4* __restrict__ txo4, const float4* __restrict__ txi4,
    const float* __restrict__ Wz, const float* __restrict__ bz,
    const float* __restrict__ Wh, const float* __restrict__ bh,
    const float* __restrict__ Wlin, const float* __restrict__ blin,
    float* __restrict__ out) {
    __shared__ float s_wzT[64 * WT_STRIDE];  // 25.6 KB
    __shared__ float s_whT[64 * WT_STRIDE];  // 25.6 KB
    __shared__ float s_in[DN_GROUP * 96];    // 24.0 KB

    int tid = threadIdx.x;
    int o = tid & 63, w = tid >> 6;
    float bzo = bz[o], bho = bh[o], wlo = Wlin[o], bl = blin[0];

    for (int idx = tid; idx < 96 * 64; idx += 256) {
        int k = idx >> 6, oo = idx & 63;
        int slab = k >> 5, c = k & 31;
        float wz, wh;
        if (slab == 0) {
            wz = Wz[c * 64 + oo] + Wz[(2 * 96 + c) * 64 + oo];
            wh = Wh[c * 64 + oo] + Wh[(2 * 96 + c) * 64 + oo];
        } else if (slab == 1) {
            wz = Wz[(96 + c) * 64 + oo];
            wh = Wh[(96 + c) * 64 + oo];
        } else {
            wz = Wz[(3 * 96 + c) * 64 + oo];
            wh = Wh[(3 * 96 + c) * 64 + oo];
        }
        s_wzT[oo * WT_STRIDE + k] = wz;
        s_whT[oo * WT_STRIDE + k] = wh;
    }

    int node0 = blockIdx.x * DN_GROUP;
    for (int idx = tid; idx < DN_GROUP * 24; idx += 256) {
        int nl = idx / 24, q = idx - nl * 24;
        int node = node0 + nl;
        float4 v = make_float4(0.f, 0.f, 0.f, 0.f);
        if (node < N_NODES) {
            if (q < 8)       v = x4[node * 8 + q];
            else if (q < 16) v = txo4[node * 8 + (q - 8)];
            else             v = txi4[node * 8 + (q - 16)];
        }
        *(float4*)&s_in[nl * 96 + q * 4] = v;
    }
    __syncthreads();

    float accz[16], acch[16];
#pragma unroll
    for (int n = 0; n < 16; ++n) { accz[n] = bzo; acch[n] = bho; }
    const float* wzp = &s_wzT[o * WT_STRIDE];
    const float* whp = &s_whT[o * WT_STRIDE];
    const float* inp = &s_in[w * 16 * 96];

    for (int kq = 0; kq < 24; ++kq) {
        float4 wz = *(const float4*)&wzp[kq * 4];
        float4 wh = *(const float4*)&whp[kq * 4];
#pragma unroll
        for (int n = 0; n < 16; ++n) {
            float4 xk = *(const float4*)&inp[n * 96 + kq * 4];
            accz[n] += xk.x * wz.x + xk.y * wz.y + xk.z * wz.z + xk.w * wz.w;
            acch[n] += xk.x * wh.x + xk.y * wh.y + xk.z * wh.z + xk.w * wh.w;
        }
    }

#pragma unroll
    for (int n = 0; n < 16; ++n) {
        float z = 1.f / (1.f + __expf(-accz[n]));
        float ht = 1.f - 2.f / (__expf(2.f * acch[n]) + 1.f);
        float rr = fmaxf((1.f - z) * ht, 0.f) * wlo;
#pragma unroll
        for (int off = 32; off > 0; off >>= 1)
            rr += __shfl_down(rr, off, 64);
        if (o == 0) {
            int node = node0 + w * 16 + n;
            if (node < N_NODES) out[node] = rr + bl;
        }
    }
}

extern "C" void kernel_launch(void* const* d_in, const int* in_sizes, int n_in,
                              void* d_out, int out_size, void* d_ws, size_t ws_size,
                              hipStream_t stream) {
    const float* x = (const float*)d_in[0];
    const int* ei = (const int*)d_in[1];
    const float* ew = (const float*)d_in[2];
    const float* Wz = (const float*)d_in[3];
    const float* bz = (const float*)d_in[4];
    // d_in[5]=Wr, d_in[6]=br dead: H0==0 makes the reset gate a no-op
    const float* Wh = (const float*)d_in[7];
    const float* bh = (const float*)d_in[8];
    const float* Wlin = (const float*)d_in[9];
    const float* blin = (const float*)d_in[10];
    float* out = (float*)d_out;
    float* wf = (float*)d_ws;
    int* wi = (int*)d_ws;

    // 1. zero the 800000 sub-bucket counters (3.2 MB)
    zero_kernel<<<196, 256, 0, stream>>>((float4*)(wf + WS_CUR_COL), 800000 / 4);
    // 2. sub-bucket counts (2 int atomics/edge, ~4-way contention)
    count_kernel<<<(N_EDGES + 255) / 256, 256, 0, stream>>>(
        ei, wi + WS_CUR_COL, wi + WS_CUR_ROW);
    // 3. in-place scan: counts -> start offsets
    scan_kernel<<<2, 1024, 0, stream>>>(wi);
    // 4. bucket-sort (src, w) by destination; counters -> end offsets
    scatter_kernel<<<(N_EDGES + 255) / 256, 256, 0, stream>>>(
        ei, ew, wi + WS_CUR_COL, wi + WS_CUR_ROW,
        (int2*)(wi + WS_PAIR_COL), (int2*)(wi + WS_PAIR_ROW));
    // 5. degrees from sorted lists -> reciprocals (no atomics)
    deg_kernel<<<2 * BLOCKS_PER_DIR, 256, 0, stream>>>(wi, wf);
    // 6a. gather dir 0: col lists x rdeg_out -> Tx_o
    gather_kernel<<<BLOCKS_PER_DIR, 256, 0, stream>>>(
        (const float4*)x, wi + WS_CUR_COL, (const int2*)(wi + WS_PAIR_COL),
        wf + WS_RDEG_OUT, (float4*)(wf + WS_TXO));
    // 6b. gather dir 1: row lists x rdeg_in -> Tx_i (writes over dead pair_col)
    gather_kernel<<<BLOCKS_PER_DIR, 256, 0, stream>>>(
        (const float4*)x, wi + WS_CUR_ROW, (const int2*)(wi + WS_PAIR_ROW),
        wf + WS_RDEG_IN, (float4*)(wf + WS_TXI));
    // 7. fused dense epilogue
    dense_kernel<<<DN_BLOCKS, 256, 0, stream>>>(
        (const float4*)x, (const float4*)(wf + WS_TXO), (const float4*)(wf + WS_TXI),
        Wz, bz, Wh, bh, Wlin, blin, out);
}

// Round 6
// 624.973 us; speedup vs baseline: 2.0169x; 2.0169x over previous
//
#include <hip/hip_runtime.h>
#include <math.h>

#define N_NODES 50000
#define N_EDGES 1600000
#define IN_CH 32
#define HID 64

// ---------------- workspace layout (float/int element offsets into d_ws)
// Counting sort with 8 sub-buckets per node (bucket = e&7). The col and row
// counter arrays are CONTIGUOUS and scanned as ONE combined 800k exclusive
// scan, so row offsets land pre-shifted by N_EDGES into a single combined
// pair buffer. Scatter bumps counters to end offsets; deg/gather derive each
// node's range as [node==0 ? base0 : cur[node*8-1], cur[node*8+7]].
#define WS_RDEG_OUT  0          // 50000 f  (1/deg_out, from row lists)
#define WS_RDEG_IN   50000      // 50000 f  (1/deg_in,  from col lists)
#define WS_CUR_COL   100000     // 400000 i (per-node x8 sub-bucket counters, col dir)
#define WS_CUR_ROW   500000     // 400000 i (row dir; contiguous after col)
#define WS_PAIR      900000     // 6400000 i : int2 (src, w_bits); col lists then row lists
#define WS_TXO       7300000    // 1600000 f (50000 x 32)
#define WS_TXI       900000     // 1600000 f -- ALIASES col-pair region (dead by then)
#define WS_BLKSUM    8900000    // 256 i scan block sums
#define WS_HIGH      8900256    // 35.6 MB high-water ( < proven 40 MB budget)

__global__ void zero_kernel(float4* __restrict__ p, int n4) {
    int i = blockIdx.x * blockDim.x + threadIdx.x;
    int stride = gridDim.x * blockDim.x;
    for (; i < n4; i += stride) p[i] = make_float4(0.f, 0.f, 0.f, 0.f);
}

// sub-bucket counts only: 2 int atomics / edge, ~4-way contention
__global__ void count_kernel(const int* __restrict__ ei,
                             int* __restrict__ cur_col, int* __restrict__ cur_row) {
    int e = blockIdx.x * blockDim.x + threadIdx.x;
    if (e >= N_EDGES) return;
    int r = ei[e];
    int c = ei[N_EDGES + e];
    int b = e & 7;
    atomicAdd(&cur_col[c * 8 + b], 1);
    atomicAdd(&cur_row[r * 8 + b], 1);
}

// ---- 3-phase multi-block exclusive scan over the combined 800000 counters ----
#define SCAN_N 800000
#define SCAN_N4 (SCAN_N / 4)          // 200000 int4
#define SCAN_PER_BLOCK 4096           // ints per block (1024 int4)
#define SCAN_BLOCKS ((SCAN_N + SCAN_PER_BLOCK - 1) / SCAN_PER_BLOCK)  // 196

__global__ __launch_bounds__(256) void scan_partial_kernel(
    const int4* __restrict__ cnt4, int* __restrict__ blksum) {
    __shared__ int s[256];
    int t = threadIdx.x;
    int base4 = blockIdx.x * 1024 + t * 4;
    int total = 0;
#pragma unroll
    for (int j = 0; j < 4; ++j) {
        int idx = base4 + j;
        if (idx < SCAN_N4) {
            int4 v = cnt4[idx];
            total += v.x + v.y + v.z + v.w;
        }
    }
    s[t] = total;
    __syncthreads();
    for (int off = 128; off > 0; off >>= 1) {
        if (t < off) s[t] += s[t + off];
        __syncthreads();
    }
    if (t == 0) blksum[blockIdx.x] = s[0];
}

__global__ __launch_bounds__(256) void scan_blocksum_kernel(int* __restrict__ blksum) {
    __shared__ int s[256];
    int t = threadIdx.x;
    int v = (t < SCAN_BLOCKS) ? blksum[t] : 0;
    s[t] = v;
    __syncthreads();
    for (int off = 1; off < 256; off <<= 1) {
        int u = (t >= off) ? s[t - off] : 0;
        __syncthreads();
        s[t] += u;
        __syncthreads();
    }
    if (t < SCAN_BLOCKS) blksum[t] = s[t] - v;  // exclusive
}

__global__ __launch_bounds__(256) void scan_final_kernel(
    int4* __restrict__ cnt4, const int* __restrict__ blksum) {
    __shared__ int s[256];
    int t = threadIdx.x;
    int base4 = blockIdx.x * 1024 + t * 4;
    int4 vals[4];
    int total = 0;
#pragma unroll
    for (int j = 0; j < 4; ++j) {
        int idx = base4 + j;
        vals[j] = (idx < SCAN_N4) ? cnt4[idx] : make_int4(0, 0, 0, 0);
        total += vals[j].x + vals[j].y + vals[j].z + vals[j].w;
    }
    s[t] = total;
    __syncthreads();
    for (int off = 1; off < 256; off <<= 1) {
        int u = (t >= off) ? s[t - off] : 0;
        __syncthreads();
        s[t] += u;
        __syncthreads();
    }
    int run = blksum[blockIdx.x] + s[t] - total;  // exclusive prefix for this thread
#pragma unroll
    for (int j = 0; j < 4; ++j) {
        int idx = base4 + j;
        int4 v = vals[j];
        int4 o;
        o.x = run; run += v.x;
        o.y = run; run += v.y;
        o.z = run; run += v.z;
        o.w = run; run += v.w;
        if (idx < SCAN_N4) cnt4[idx] = o;
    }
}

// bucket-sort edges by destination into the combined pair buffer
__global__ void scatter_kernel(const int* __restrict__ ei, const float* __restrict__ ew,
                               int* __restrict__ cur_col, int* __restrict__ cur_row,
                               int2* __restrict__ pair) {
    int e = blockIdx.x * blockDim.x + threadIdx.x;
    if (e >= N_EDGES) return;
    int r = ei[e];
    int c = ei[N_EDGES + e];
    int wb = __float_as_int(ew[e]);
    int b = e & 7;
    int p = atomicAdd(&cur_col[c * 8 + b], 1);
    pair[p] = make_int2(r, wb);
    int q = atomicAdd(&cur_row[r * 8 + b], 1);  // lands at >= N_EDGES (combined scan)
    pair[q] = make_int2(c, wb);
}

#define GROUPS_PER_BLOCK 32
#define BLOCKS_PER_DIR ((N_NODES + GROUPS_PER_BLOCK - 1) / GROUPS_PER_BLOCK)  // 1563

// per-node degree = sum of w over its sorted list; write reciprocal.
// dir 0: col lists -> rdeg_in ; dir 1: row lists -> rdeg_out. 8 lanes/node.
__global__ __launch_bounds__(256) void deg_kernel(const int* __restrict__ ws_i,
                                                  float* __restrict__ ws_f) {
    int bidx = blockIdx.x;
    int dir = (bidx >= BLOCKS_PER_DIR) ? 1 : 0;
    int node = (bidx - dir * BLOCKS_PER_DIR) * GROUPS_PER_BLOCK + (threadIdx.x >> 3);
    if (node >= N_NODES) return;
    int lane = threadIdx.x & 7;
    const int* cur = ws_i + (dir == 0 ? WS_CUR_COL : WS_CUR_ROW);
    const int2* pair = (const int2*)(ws_i + WS_PAIR);
    float* rdeg = ws_f + (dir == 0 ? WS_RDEG_IN : WS_RDEG_OUT);
    int base0 = dir == 0 ? 0 : N_EDGES;

    int start = (node == 0) ? base0 : cur[node * 8 - 1];
    int end = cur[node * 8 + 7];
    float s = 0.f;
    for (int p = start + lane; p < end; p += 8) s += __int_as_float(pair[p].y);
    s += __shfl_down(s, 4, 8);
    s += __shfl_down(s, 2, 8);
    s += __shfl_down(s, 1, 8);
    if (lane == 0) rdeg[node] = (s != 0.f) ? (1.f / s) : 0.f;
}

// register-accumulating gather: 8 lanes per node, one float4 of channels each.
// coef = w * rdeg[src] (rdeg: 200 KB L2-resident table).
__global__ __launch_bounds__(256) void gather_kernel(
    const float4* __restrict__ x4, const int* __restrict__ cur, int base0,
    const int2* __restrict__ pair, const float* __restrict__ rdeg,
    float4* __restrict__ outp) {
    int node = blockIdx.x * GROUPS_PER_BLOCK + (threadIdx.x >> 3);
    if (node >= N_NODES) return;
    int lane = threadIdx.x & 7;

    int p = (node == 0) ? base0 : cur[node * 8 - 1];
    int end = cur[node * 8 + 7];
    float4 acc = make_float4(0.f, 0.f, 0.f, 0.f);
    for (; p + 1 < end; p += 2) {
        int2 e0 = pair[p], e1 = pair[p + 1];
        float c0 = __int_as_float(e0.y) * rdeg[e0.x];
        float c1 = __int_as_float(e1.y) * rdeg[e1.x];
        float4 a = x4[e0.x * 8 + lane];
        float4 bb = x4[e1.x * 8 + lane];
        acc.x += c0 * a.x + c1 * bb.x;
        acc.y += c0 * a.y + c1 * bb.y;
        acc.z += c0 * a.z + c1 * bb.z;
        acc.w += c0 * a.w + c1 * bb.w;
    }
    if (p < end) {
        int2 e0 = pair[p];
        float c0 = __int_as_float(e0.y) * rdeg[e0.x];
        float4 a = x4[e0.x * 8 + lane];
        acc.x += c0 * a.x;
        acc.y += c0 * a.y;
        acc.z += c0 * a.z;
        acc.w += c0 * a.w;
    }
    outp[node * 8 + lane] = acc;
}

// Fused dense epilogue (unchanged; off the top-5 since round 4):
// weights transposed in LDS [o][k] stride 100, 16-node register batch per wave.
#define DN_GROUP 64
#define DN_BLOCKS ((N_NODES + DN_GROUP - 1) / DN_GROUP)  // 782
#define WT_STRIDE 100
__global__ __launch_bounds__(256) void dense_kernel(
    const float4* __restrict__ x4,
    const float4* __restrict__ txo4, const float4* __restrict__ txi4,
    const float* __restrict__ Wz, const float* __restrict__ bz,
    const float* __restrict__ Wh, const float* __restrict__ bh,
    const float* __restrict__ Wlin, const float* __restrict__ blin,
    float* __restrict__ out) {
    __shared__ float s_wzT[64 * WT_STRIDE];  // 25.6 KB
    __shared__ float s_whT[64 * WT_STRIDE];  // 25.6 KB
    __shared__ float s_in[DN_GROUP * 96];    // 24.0 KB

    int tid = threadIdx.x;
    int o = tid & 63, w = tid >> 6;
    float bzo = bz[o], bho = bh[o], wlo = Wlin[o], bl = blin[0];

    for (int idx = tid; idx < 96 * 64; idx += 256) {
        int k = idx >> 6, oo = idx & 63;
        int slab = k >> 5, c = k & 31;
        float wz, wh;
        if (slab == 0) {
            wz = Wz[c * 64 + oo] + Wz[(2 * 96 + c) * 64 + oo];
            wh = Wh[c * 64 + oo] + Wh[(2 * 96 + c) * 64 + oo];
        } else if (slab == 1) {
            wz = Wz[(96 + c) * 64 + oo];
            wh = Wh[(96 + c) * 64 + oo];
        } else {
            wz = Wz[(3 * 96 + c) * 64 + oo];
            wh = Wh[(3 * 96 + c) * 64 + oo];
        }
        s_wzT[oo * WT_STRIDE + k] = wz;
        s_whT[oo * WT_STRIDE + k] = wh;
    }

    int node0 = blockIdx.x * DN_GROUP;
    for (int idx = tid; idx < DN_GROUP * 24; idx += 256) {
        int nl = idx / 24, q = idx - nl * 24;
        int node = node0 + nl;
        float4 v = make_float4(0.f, 0.f, 0.f, 0.f);
        if (node < N_NODES) {
            if (q < 8)       v = x4[node * 8 + q];
            else if (q < 16) v = txo4[node * 8 + (q - 8)];
            else             v = txi4[node * 8 + (q - 16)];
        }
        *(float4*)&s_in[nl * 96 + q * 4] = v;
    }
    __syncthreads();

    float accz[16], acch[16];
#pragma unroll
    for (int n = 0; n < 16; ++n) { accz[n] = bzo; acch[n] = bho; }
    const float* wzp = &s_wzT[o * WT_STRIDE];
    const float* whp = &s_whT[o * WT_STRIDE];
    const float* inp = &s_in[w * 16 * 96];

    for (int kq = 0; kq < 24; ++kq) {
        float4 wz = *(const float4*)&wzp[kq * 4];
        float4 wh = *(const float4*)&whp[kq * 4];
#pragma unroll
        for (int n = 0; n < 16; ++n) {
            float4 xk = *(const float4*)&inp[n * 96 + kq * 4];
            accz[n] += xk.x * wz.x + xk.y * wz.y + xk.z * wz.z + xk.w * wz.w;
            acch[n] += xk.x * wh.x + xk.y * wh.y + xk.z * wh.z + xk.w * wh.w;
        }
    }

#pragma unroll
    for (int n = 0; n < 16; ++n) {
        float z = 1.f / (1.f + __expf(-accz[n]));
        float ht = 1.f - 2.f / (__expf(2.f * acch[n]) + 1.f);
        float rr = fmaxf((1.f - z) * ht, 0.f) * wlo;
#pragma unroll
        for (int off = 32; off > 0; off >>= 1)
            rr += __shfl_down(rr, off, 64);
        if (o == 0) {
            int node = node0 + w * 16 + n;
            if (node < N_NODES) out[node] = rr + bl;
        }
    }
}

extern "C" void kernel_launch(void* const* d_in, const int* in_sizes, int n_in,
                              void* d_out, int out_size, void* d_ws, size_t ws_size,
                              hipStream_t stream) {
    const float* x = (const float*)d_in[0];
    const int* ei = (const int*)d_in[1];
    const float* ew = (const float*)d_in[2];
    const float* Wz = (const float*)d_in[3];
    const float* bz = (const float*)d_in[4];
    // d_in[5]=Wr, d_in[6]=br dead: H0==0 makes the reset gate a no-op
    const float* Wh = (const float*)d_in[7];
    const float* bh = (const float*)d_in[8];
    const float* Wlin = (const float*)d_in[9];
    const float* blin = (const float*)d_in[10];
    float* out = (float*)d_out;
    float* wf = (float*)d_ws;
    int* wi = (int*)d_ws;

    // 1. zero the 800000 sub-bucket counters (3.2 MB)
    zero_kernel<<<196, 256, 0, stream>>>((float4*)(wf + WS_CUR_COL), SCAN_N / 4);
    // 2. sub-bucket counts (2 int atomics/edge, ~4-way contention)
    count_kernel<<<(N_EDGES + 255) / 256, 256, 0, stream>>>(
        ei, wi + WS_CUR_COL, wi + WS_CUR_ROW);
    // 3. combined 800k exclusive scan, 3 phases (round-5 fix: was 2-block serial)
    scan_partial_kernel<<<SCAN_BLOCKS, 256, 0, stream>>>(
        (const int4*)(wi + WS_CUR_COL), wi + WS_BLKSUM);
    scan_blocksum_kernel<<<1, 256, 0, stream>>>(wi + WS_BLKSUM);
    scan_final_kernel<<<SCAN_BLOCKS, 256, 0, stream>>>(
        (int4*)(wi + WS_CUR_COL), wi + WS_BLKSUM);
    // 4. bucket-sort (src, w) by destination; counters -> end offsets
    scatter_kernel<<<(N_EDGES + 255) / 256, 256, 0, stream>>>(
        ei, ew, wi + WS_CUR_COL, wi + WS_CUR_ROW, (int2*)(wi + WS_PAIR));
    // 5. degrees from sorted lists -> reciprocals (no atomics)
    deg_kernel<<<2 * BLOCKS_PER_DIR, 256, 0, stream>>>(wi, wf);
    // 6a. gather dir 0: col lists x rdeg_out -> Tx_o
    gather_kernel<<<BLOCKS_PER_DIR, 256, 0, stream>>>(
        (const float4*)x, wi + WS_CUR_COL, 0, (const int2*)(wi + WS_PAIR),
        wf + WS_RDEG_OUT, (float4*)(wf + WS_TXO));
    // 6b. gather dir 1: row lists x rdeg_in -> Tx_i (writes over dead col-pair region)
    gather_kernel<<<BLOCKS_PER_DIR, 256, 0, stream>>>(
        (const float4*)x, wi + WS_CUR_ROW, N_EDGES, (const int2*)(wi + WS_PAIR),
        wf + WS_RDEG_IN, (float4*)(wf + WS_TXI));
    // 7. fused dense epilogue
    dense_kernel<<<DN_BLOCKS, 256, 0, stream>>>(
        (const float4*)x, (const float4*)(wf + WS_TXO), (const float4*)(wf + WS_TXI),
        Wz, bz, Wh, bh, Wlin, blin, out);
}

// Round 7
// 418.146 us; speedup vs baseline: 3.0145x; 1.4946x over previous
//
#include <hip/hip_runtime.h>
#include <math.h>

#define N_NODES 50000
#define N_EDGES 1600000
#define IN_CH 32
#define HID 64

// ---------------- workspace layout (float/int element offsets into d_ws)
// Counting sort, 8 sub-buckets per node (bucket = e&7). Col and row counter
// arrays are contiguous -> ONE combined 800k exclusive scan; row offsets land
// pre-shifted by N_EDGES in the combined pair buffer. Ranks captured during
// the count pass (atomic return values, packed 16b row | 16b col) make the
// scatter pass ATOMIC-FREE: pos = offs[bucket] + rank. Counters therefore
// remain START offsets after scatter; node ranges = [cur[idx], cur[idx+8])
// with idx = dir*400000 + node*8 (end of last list = 2*N_EDGES).
#define WS_RDEG_OUT  0          // 50000 f  (1/deg_out, from row lists)
#define WS_RDEG_IN   50000      // 50000 f  (1/deg_in,  from col lists)
#define WS_CUR       100000     // 800000 i (col counters then row counters)
#define WS_PAIR      900000     // 6400000 i : int2 (src, w_bits); col lists then row lists
#define WS_TXO       7300000    // 1600000 f (50000 x 32)
#define WS_RANK      7300000    // 1600000 i -- ALIASES TXO (rank dead before gather writes)
#define WS_TXI       900000     // 1600000 f -- ALIASES col-pair half (dead by gather dir 1)
#define WS_BLKSUM    8900000    // 256 i scan block sums
#define WS_HIGH      8900256    // 35.6 MB high-water

__global__ void zero_kernel(float4* __restrict__ p, int n4) {
    int i = blockIdx.x * blockDim.x + threadIdx.x;
    int stride = gridDim.x * blockDim.x;
    for (; i < n4; i += stride) p[i] = make_float4(0.f, 0.f, 0.f, 0.f);
}

// sub-bucket counts + rank capture: 2 int atomics / edge; the returned old
// values ARE the per-bucket ranks -- packed (row<<16)|col into one coalesced
// store. Sub-bucket occupancy ~Poisson(4) => ranks << 65536.
__global__ void count_kernel(const int* __restrict__ ei,
                             int* __restrict__ cur, int* __restrict__ rank) {
    int e = blockIdx.x * blockDim.x + threadIdx.x;
    if (e >= N_EDGES) return;
    int r = ei[e];
    int c = ei[N_EDGES + e];
    int b = e & 7;
    int rc = atomicAdd(&cur[c * 8 + b], 1);
    int rr = atomicAdd(&cur[400000 + r * 8 + b], 1);
    rank[e] = (rr << 16) | rc;
}

// ---- 3-phase multi-block exclusive scan over the combined 800000 counters ----
#define SCAN_N 800000
#define SCAN_N4 (SCAN_N / 4)          // 200000 int4
#define SCAN_PER_BLOCK 4096           // ints per block (1024 int4)
#define SCAN_BLOCKS ((SCAN_N + SCAN_PER_BLOCK - 1) / SCAN_PER_BLOCK)  // 196

__global__ __launch_bounds__(256) void scan_partial_kernel(
    const int4* __restrict__ cnt4, int* __restrict__ blksum) {
    __shared__ int s[256];
    int t = threadIdx.x;
    int base4 = blockIdx.x * 1024 + t * 4;
    int total = 0;
#pragma unroll
    for (int j = 0; j < 4; ++j) {
        int idx = base4 + j;
        if (idx < SCAN_N4) {
            int4 v = cnt4[idx];
            total += v.x + v.y + v.z + v.w;
        }
    }
    s[t] = total;
    __syncthreads();
    for (int off = 128; off > 0; off >>= 1) {
        if (t < off) s[t] += s[t + off];
        __syncthreads();
    }
    if (t == 0) blksum[blockIdx.x] = s[0];
}

__global__ __launch_bounds__(256) void scan_blocksum_kernel(int* __restrict__ blksum) {
    __shared__ int s[256];
    int t = threadIdx.x;
    int v = (t < SCAN_BLOCKS) ? blksum[t] : 0;
    s[t] = v;
    __syncthreads();
    for (int off = 1; off < 256; off <<= 1) {
        int u = (t >= off) ? s[t - off] : 0;
        __syncthreads();
        s[t] += u;
        __syncthreads();
    }
    if (t < SCAN_BLOCKS) blksum[t] = s[t] - v;  // exclusive
}

__global__ __launch_bounds__(256) void scan_final_kernel(
    int4* __restrict__ cnt4, const int* __restrict__ blksum) {
    __shared__ int s[256];
    int t = threadIdx.x;
    int base4 = blockIdx.x * 1024 + t * 4;
    int4 vals[4];
    int total = 0;
#pragma unroll
    for (int j = 0; j < 4; ++j) {
        int idx = base4 + j;
        vals[j] = (idx < SCAN_N4) ? cnt4[idx] : make_int4(0, 0, 0, 0);
        total += vals[j].x + vals[j].y + vals[j].z + vals[j].w;
    }
    s[t] = total;
    __syncthreads();
    for (int off = 1; off < 256; off <<= 1) {
        int u = (t >= off) ? s[t - off] : 0;
        __syncthreads();
        s[t] += u;
        __syncthreads();
    }
    int run = blksum[blockIdx.x] + s[t] - total;  // exclusive prefix for this thread
#pragma unroll
    for (int j = 0; j < 4; ++j) {
        int idx = base4 + j;
        int4 v = vals[j];
        int4 o;
        o.x = run; run += v.x;
        o.y = run; run += v.y;
        o.z = run; run += v.z;
        o.w = run; run += v.w;
        if (idx < SCAN_N4) cnt4[idx] = o;
    }
}

// ATOMIC-FREE bucket-sort: position = start_offset[bucket] + captured rank.
__global__ void scatter_kernel(const int* __restrict__ ei, const float* __restrict__ ew,
                               const int* __restrict__ cur, const int* __restrict__ rank,
                               int2* __restrict__ pair) {
    int e = blockIdx.x * blockDim.x + threadIdx.x;
    if (e >= N_EDGES) return;
    int r = ei[e];
    int c = ei[N_EDGES + e];
    int wb = __float_as_int(ew[e]);
    int b = e & 7;
    int pk = rank[e];
    int p = cur[c * 8 + b] + (pk & 0xffff);
    int q = cur[400000 + r * 8 + b] + (pk >> 16);
    pair[p] = make_int2(r, wb);
    pair[q] = make_int2(c, wb);
}

#define GROUPS_PER_BLOCK 32
#define BLOCKS_PER_DIR ((N_NODES + GROUPS_PER_BLOCK - 1) / GROUPS_PER_BLOCK)  // 1563

// per-node degree = sum of w over its sorted list; write reciprocal.
// dir 0: col lists -> rdeg_in ; dir 1: row lists -> rdeg_out. 8 lanes/node.
__global__ __launch_bounds__(256) void deg_kernel(const int* __restrict__ ws_i,
                                                  float* __restrict__ ws_f) {
    int bidx = blockIdx.x;
    int dir = (bidx >= BLOCKS_PER_DIR) ? 1 : 0;
    int node = (bidx - dir * BLOCKS_PER_DIR) * GROUPS_PER_BLOCK + (threadIdx.x >> 3);
    if (node >= N_NODES) return;
    int lane = threadIdx.x & 7;
    const int* cur = ws_i + WS_CUR;
    const int2* pair = (const int2*)(ws_i + WS_PAIR);
    float* rdeg = ws_f + (dir == 0 ? WS_RDEG_IN : WS_RDEG_OUT);

    int idx = dir * 400000 + node * 8;
    int start = cur[idx];
    int end = (idx + 8 < SCAN_N) ? cur[idx + 8] : 2 * N_EDGES;
    float s = 0.f;
    for (int p = start + lane; p < end; p += 8) s += __int_as_float(pair[p].y);
    s += __shfl_down(s, 4, 8);
    s += __shfl_down(s, 2, 8);
    s += __shfl_down(s, 1, 8);
    if (lane == 0) rdeg[node] = (s != 0.f) ? (1.f / s) : 0.f;
}

// register-accumulating gather: 8 lanes per node, one float4 of channels each.
// coef = w * rdeg[src] (rdeg: 200 KB L2-resident table).
__global__ __launch_bounds__(256) void gather_kernel(
    const float4* __restrict__ x4, const int* __restrict__ cur, int dirbase,
    const int2* __restrict__ pair, const float* __restrict__ rdeg,
    float4* __restrict__ outp) {
    int node = blockIdx.x * GROUPS_PER_BLOCK + (threadIdx.x >> 3);
    if (node >= N_NODES) return;
    int lane = threadIdx.x & 7;

    int idx = dirbase + node * 8;
    int p = cur[idx];
    int end = (idx + 8 < SCAN_N) ? cur[idx + 8] : 2 * N_EDGES;
    float4 acc = make_float4(0.f, 0.f, 0.f, 0.f);
    for (; p + 1 < end; p += 2) {
        int2 e0 = pair[p], e1 = pair[p + 1];
        float c0 = __int_as_float(e0.y) * rdeg[e0.x];
        float c1 = __int_as_float(e1.y) * rdeg[e1.x];
        float4 a = x4[e0.x * 8 + lane];
        float4 bb = x4[e1.x * 8 + lane];
        acc.x += c0 * a.x + c1 * bb.x;
        acc.y += c0 * a.y + c1 * bb.y;
        acc.z += c0 * a.z + c1 * bb.z;
        acc.w += c0 * a.w + c1 * bb.w;
    }
    if (p < end) {
        int2 e0 = pair[p];
        float c0 = __int_as_float(e0.y) * rdeg[e0.x];
        float4 a = x4[e0.x * 8 + lane];
        acc.x += c0 * a.x;
        acc.y += c0 * a.y;
        acc.z += c0 * a.z;
        acc.w += c0 * a.w;
    }
    outp[node * 8 + lane] = acc;
}

// Fused dense epilogue (unchanged; off the top-5 since round 4):
// weights transposed in LDS [o][k] stride 100, 16-node register batch per wave.
#define DN_GROUP 64
#define DN_BLOCKS ((N_NODES + DN_GROUP - 1) / DN_GROUP)  // 782
#define WT_STRIDE 100
__global__ __launch_bounds__(256) void dense_kernel(
    const float4* __restrict__ x4,
    const float4* __restrict__ txo4, const float4* __restrict__ txi4,
    const float* __restrict__ Wz, const float* __restrict__ bz,
    const float* __restrict__ Wh, const float* __restrict__ bh,
    const float* __restrict__ Wlin, const float* __restrict__ blin,
    float* __restrict__ out) {
    __shared__ float s_wzT[64 * WT_STRIDE];  // 25.6 KB
    __shared__ float s_whT[64 * WT_STRIDE];  // 25.6 KB
    __shared__ float s_in[DN_GROUP * 96];    // 24.0 KB

    int tid = threadIdx.x;
    int o = tid & 63, w = tid >> 6;
    float bzo = bz[o], bho = bh[o], wlo = Wlin[o], bl = blin[0];

    for (int idx = tid; idx < 96 * 64; idx += 256) {
        int k = idx >> 6, oo = idx & 63;
        int slab = k >> 5, c = k & 31;
        float wz, wh;
        if (slab == 0) {
            wz = Wz[c * 64 + oo] + Wz[(2 * 96 + c) * 64 + oo];
            wh = Wh[c * 64 + oo] + Wh[(2 * 96 + c) * 64 + oo];
        } else if (slab == 1) {
            wz = Wz[(96 + c) * 64 + oo];
            wh = Wh[(96 + c) * 64 + oo];
        } else {
            wz = Wz[(3 * 96 + c) * 64 + oo];
            wh = Wh[(3 * 96 + c) * 64 + oo];
        }
        s_wzT[oo * WT_STRIDE + k] = wz;
        s_whT[oo * WT_STRIDE + k] = wh;
    }

    int node0 = blockIdx.x * DN_GROUP;
    for (int idx = tid; idx < DN_GROUP * 24; idx += 256) {
        int nl = idx / 24, q = idx - nl * 24;
        int node = node0 + nl;
        float4 v = make_float4(0.f, 0.f, 0.f, 0.f);
        if (node < N_NODES) {
            if (q < 8)       v = x4[node * 8 + q];
            else if (q < 16) v = txo4[node * 8 + (q - 8)];
            else             v = txi4[node * 8 + (q - 16)];
        }
        *(float4*)&s_in[nl * 96 + q * 4] = v;
    }
    __syncthreads();

    float accz[16], acch[16];
#pragma unroll
    for (int n = 0; n < 16; ++n) { accz[n] = bzo; acch[n] = bho; }
    const float* wzp = &s_wzT[o * WT_STRIDE];
    const float* whp = &s_whT[o * WT_STRIDE];
    const float* inp = &s_in[w * 16 * 96];

    for (int kq = 0; kq < 24; ++kq) {
        float4 wz = *(const float4*)&wzp[kq * 4];
        float4 wh = *(const float4*)&whp[kq * 4];
#pragma unroll
        for (int n = 0; n < 16; ++n) {
            float4 xk = *(const float4*)&inp[n * 96 + kq * 4];
            accz[n] += xk.x * wz.x + xk.y * wz.y + xk.z * wz.z + xk.w * wz.w;
            acch[n] += xk.x * wh.x + xk.y * wh.y + xk.z * wh.z + xk.w * wh.w;
        }
    }

#pragma unroll
    for (int n = 0; n < 16; ++n) {
        float z = 1.f / (1.f + __expf(-accz[n]));
        float ht = 1.f - 2.f / (__expf(2.f * acch[n]) + 1.f);
        float rr = fmaxf((1.f - z) * ht, 0.f) * wlo;
#pragma unroll
        for (int off = 32; off > 0; off >>= 1)
            rr += __shfl_down(rr, off, 64);
        if (o == 0) {
            int node = node0 + w * 16 + n;
            if (node < N_NODES) out[node] = rr + bl;
        }
    }
}

extern "C" void kernel_launch(void* const* d_in, const int* in_sizes, int n_in,
                              void* d_out, int out_size, void* d_ws, size_t ws_size,
                              hipStream_t stream) {
    const float* x = (const float*)d_in[0];
    const int* ei = (const int*)d_in[1];
    const float* ew = (const float*)d_in[2];
    const float* Wz = (const float*)d_in[3];
    const float* bz = (const float*)d_in[4];
    // d_in[5]=Wr, d_in[6]=br dead: H0==0 makes the reset gate a no-op
    const float* Wh = (const float*)d_in[7];
    const float* bh = (const float*)d_in[8];
    const float* Wlin = (const float*)d_in[9];
    const float* blin = (const float*)d_in[10];
    float* out = (float*)d_out;
    float* wf = (float*)d_ws;
    int* wi = (int*)d_ws;

    // 1. zero the 800000 sub-bucket counters (3.2 MB)
    zero_kernel<<<196, 256, 0, stream>>>((float4*)(wf + WS_CUR), SCAN_N / 4);
    // 2. sub-bucket counts + packed rank capture (2 int atomics/edge)
    count_kernel<<<(N_EDGES + 255) / 256, 256, 0, stream>>>(
        ei, wi + WS_CUR, wi + WS_RANK);
    // 3. combined 800k exclusive scan, 3 phases
    scan_partial_kernel<<<SCAN_BLOCKS, 256, 0, stream>>>(
        (const int4*)(wi + WS_CUR), wi + WS_BLKSUM);
    scan_blocksum_kernel<<<1, 256, 0, stream>>>(wi + WS_BLKSUM);
    scan_final_kernel<<<SCAN_BLOCKS, 256, 0, stream>>>(
        (int4*)(wi + WS_CUR), wi + WS_BLKSUM);
    // 4. ATOMIC-FREE bucket-sort via offs[bucket] + rank (counters stay start offsets)
    scatter_kernel<<<(N_EDGES + 255) / 256, 256, 0, stream>>>(
        ei, ew, wi + WS_CUR, wi + WS_RANK, (int2*)(wi + WS_PAIR));
    // 5. degrees from sorted lists -> reciprocals (no atomics)
    deg_kernel<<<2 * BLOCKS_PER_DIR, 256, 0, stream>>>(wi, wf);
    // 6a. gather dir 0: col lists x rdeg_out -> Tx_o (overwrites dead rank region)
    gather_kernel<<<BLOCKS_PER_DIR, 256, 0, stream>>>(
        (const float4*)x, wi + WS_CUR, 0, (const int2*)(wi + WS_PAIR),
        wf + WS_RDEG_OUT, (float4*)(wf + WS_TXO));
    // 6b. gather dir 1: row lists x rdeg_in -> Tx_i (overwrites dead col-pair half)
    gather_kernel<<<BLOCKS_PER_DIR, 256, 0, stream>>>(
        (const float4*)x, wi + WS_CUR, 400000, (const int2*)(wi + WS_PAIR),
        wf + WS_RDEG_IN, (float4*)(wf + WS_TXI));
    // 7. fused dense epilogue
    dense_kernel<<<DN_BLOCKS, 256, 0, stream>>>(
        (const float4*)x, (const float4*)(wf + WS_TXO), (const float4*)(wf + WS_TXI),
        Wz, bz, Wh, bh, Wlin, blin, out);
}

// Round 8
// 290.246 us; speedup vs baseline: 4.3428x; 1.4407x over previous
//
#include <hip/hip_runtime.h>
#include <math.h>

#define N_NODES 50000
#define N_EDGES 1600000
#define IN_CH 32
#define HID 64

// ---------------- two-level radix partition (ZERO global atomics) ----------
// Level 1: 196 coarse bins of 256 dst-nodes (bin = dst>>8), chunked over 391
//   blocks of 4096 edges; per-(dir,bin,chunk) counts built with LDS atomics.
// Level 2: per-bin exact sort by dst via LDS 256-counter histogram + LDS scan,
//   emitting per-node offsets (node_offs) and the final dst-sorted pair lists.
// Buffer reuse: one 12.8 MB binned staging region serves dir0 then dir1, and
// is later overwritten by TXO/TXI.
#define NBIN 196
#define BIN_SHIFT 8
#define CHUNK 4096
#define NCHK ((N_EDGES + CHUNK - 1) / CHUNK)   // 391
#define CNTG_N (2 * NBIN * NCHK)               // 153272
#define CNTG_N4 (CNTG_N / 4)                   // 38318
#define SCAN_BLOCKS ((CNTG_N4 + 1023) / 1024)  // 38

// ---------------- workspace layout (int element offsets into d_ws)
#define WS_RDEG_OUT 0                          // 50000 f (from row lists, dir1)
#define WS_RDEG_IN  50000                      // 50000 f (from col lists, dir0)
#define WS_CNTG     100000                     // 153272 i (scanned in place)
#define WS_BLKSUM   253272                     // 64 i
#define WS_NOFF     253336                     // 100001 i (global positions + sentinel)
#define WS_BINNED   353340                     // 3200000 i (int2 x 1.6M, per-dir staging)
#define WS_TXO      353340                     // 1600000 f -- aliases binned (dead by gather)
#define WS_TXI      1953340                    // 1600000 f -- aliases binned tail
#define WS_PAIR0    3553340                    // 3200000 i (col-sorted: src=row, w)
#define WS_PAIR1    6753340                    // 3200000 i (row-sorted: src=col, w)
#define WS_END      9953340                    // 39.8 MB high-water (< proven 40 MB)

// 1. per-chunk coarse histograms (LDS atomics only; fully writes cntG)
__global__ __launch_bounds__(512) void hist_kernel(const int* __restrict__ ei,
                                                   int* __restrict__ cntG) {
    __shared__ int h[2 * NBIN];
    int tid = threadIdx.x;
    for (int i = tid; i < 2 * NBIN; i += 512) h[i] = 0;
    __syncthreads();
    int e0 = blockIdx.x * CHUNK;
    int e1 = min(e0 + CHUNK, N_EDGES);
    for (int e = e0 + tid; e < e1; e += 512) {
        int r = ei[e];
        int c = ei[N_EDGES + e];
        atomicAdd(&h[c >> BIN_SHIFT], 1);           // dir0: group by col
        atomicAdd(&h[NBIN + (r >> BIN_SHIFT)], 1);  // dir1: group by row
    }
    __syncthreads();
    for (int i = tid; i < 2 * NBIN; i += 512) cntG[i * NCHK + blockIdx.x] = h[i];
}

// ---- 3-phase exclusive scan over cntG (parametrized from round 6) ----
__global__ __launch_bounds__(256) void scan_partial_kernel(
    const int4* __restrict__ cnt4, int* __restrict__ blksum, int n4) {
    __shared__ int s[256];
    int t = threadIdx.x;
    int base4 = blockIdx.x * 1024 + t * 4;
    int total = 0;
#pragma unroll
    for (int j = 0; j < 4; ++j) {
        int idx = base4 + j;
        if (idx < n4) {
            int4 v = cnt4[idx];
            total += v.x + v.y + v.z + v.w;
        }
    }
    s[t] = total;
    __syncthreads();
    for (int off = 128; off > 0; off >>= 1) {
        if (t < off) s[t] += s[t + off];
        __syncthreads();
    }
    if (t == 0) blksum[blockIdx.x] = s[0];
}

__global__ __launch_bounds__(256) void scan_blocksum_kernel(int* __restrict__ blksum, int nb) {
    __shared__ int s[256];
    int t = threadIdx.x;
    int v = (t < nb) ? blksum[t] : 0;
    s[t] = v;
    __syncthreads();
    for (int off = 1; off < 256; off <<= 1) {
        int u = (t >= off) ? s[t - off] : 0;
        __syncthreads();
        s[t] += u;
        __syncthreads();
    }
    if (t < nb) blksum[t] = s[t] - v;  // exclusive
}

__global__ __launch_bounds__(256) void scan_final_kernel(
    int4* __restrict__ cnt4, const int* __restrict__ blksum, int n4) {
    __shared__ int s[256];
    int t = threadIdx.x;
    int base4 = blockIdx.x * 1024 + t * 4;
    int4 vals[4];
    int total = 0;
#pragma unroll
    for (int j = 0; j < 4; ++j) {
        int idx = base4 + j;
        vals[j] = (idx < n4) ? cnt4[idx] : make_int4(0, 0, 0, 0);
        total += vals[j].x + vals[j].y + vals[j].z + vals[j].w;
    }
    s[t] = total;
    __syncthreads();
    for (int off = 1; off < 256; off <<= 1) {
        int u = (t >= off) ? s[t - off] : 0;
        __syncthreads();
        s[t] += u;
        __syncthreads();
    }
    int run = blksum[blockIdx.x] + s[t] - total;
#pragma unroll
    for (int j = 0; j < 4; ++j) {
        int idx = base4 + j;
        int4 v = vals[j];
        int4 o;
        o.x = run; run += v.x;
        o.y = run; run += v.y;
        o.z = run; run += v.z;
        o.w = run; run += v.w;
        if (idx < n4) cnt4[idx] = o;
    }
}

// 3. coarse partition for one direction: LDS-bumped positions from scanned cntG
__global__ __launch_bounds__(512) void partition_kernel(
    const int* __restrict__ ei, const float* __restrict__ ew,
    const int* __restrict__ cntG, int2* __restrict__ binned, int dir) {
    __shared__ int cur[NBIN];
    int tid = threadIdx.x;
    for (int i = tid; i < NBIN; i += 512)
        cur[i] = cntG[(dir * NBIN + i) * NCHK + blockIdx.x] - dir * N_EDGES;
    __syncthreads();
    int e0 = blockIdx.x * CHUNK;
    int e1 = min(e0 + CHUNK, N_EDGES);
    for (int e = e0 + tid; e < e1; e += 512) {
        int r = ei[e];
        int c = ei[N_EDGES + e];
        int wb = __float_as_int(ew[e]);
        int dst = dir ? r : c;
        int src = dir ? c : r;
        int pos = atomicAdd(&cur[dst >> BIN_SHIFT], 1);  // LDS atomic
        binned[pos] = make_int2(((dst & 255) << 16) | src, wb);  // src < 65536 OK
    }
}

// 4. per-bin exact sort by dst: LDS histogram + LDS scan -> node_offs + pair
__global__ __launch_bounds__(512) void binsort_kernel(
    const int* __restrict__ cntG, const int2* __restrict__ binned,
    int2* __restrict__ pair, int* __restrict__ node_offs, int dir) {
    __shared__ int cnt[256];  // counts -> then cur (exclusive offsets)
    __shared__ int sc[256];
    int tid = threadIdx.x;
    int bin = blockIdx.x;
    int idxLin = (dir * NBIN + bin) * NCHK;
    int binStart = cntG[idxLin];  // global position
    int binEnd = (idxLin + NCHK < CNTG_N) ? cntG[idxLin + NCHK] : 2 * N_EDGES;
    int lo = binStart - dir * N_EDGES;   // local into per-dir buffers
    int hi = binEnd - dir * N_EDGES;

    for (int i = tid; i < 256; i += 512) cnt[i] = 0;
    __syncthreads();
    for (int p = lo + tid; p < hi; p += 512)
        atomicAdd(&cnt[binned[p].x >> 16], 1);
    __syncthreads();
    // exclusive scan of 256 counts (first 256 threads; all threads hit barriers)
    int v = (tid < 256) ? cnt[tid] : 0;
    if (tid < 256) sc[tid] = v;
    __syncthreads();
    for (int off = 1; off < 256; off <<= 1) {
        int u = (tid < 256 && tid >= off) ? sc[tid - off] : 0;
        __syncthreads();
        if (tid < 256) sc[tid] += u;
        __syncthreads();
    }
    if (tid < 256) {
        int excl = sc[tid] - v;
        cnt[tid] = excl;  // becomes cur
        int node = bin * 256 + tid;
        if (node < N_NODES) node_offs[dir * N_NODES + node] = binStart + excl;
    }
    if (tid == 0 && dir == 1 && bin == NBIN - 1) node_offs[2 * N_NODES] = 2 * N_EDGES;
    __syncthreads();
    for (int p = lo + tid; p < hi; p += 512) {
        int2 ed = binned[p];
        int rank = atomicAdd(&cnt[ed.x >> 16], 1);  // LDS atomic, rel. to bin start
        pair[lo + rank] = make_int2(ed.x & 0xffff, ed.y);
    }
}

#define GROUPS_PER_BLOCK 32
#define BLOCKS_PER_DIR ((N_NODES + GROUPS_PER_BLOCK - 1) / GROUPS_PER_BLOCK)  // 1563

// 5. per-node degree = sum of w over sorted list; write reciprocal.
// dir0 (col lists) -> rdeg_in ; dir1 (row lists) -> rdeg_out. 8 lanes/node.
__global__ __launch_bounds__(256) void deg_kernel(const int* __restrict__ ws_i,
                                                  float* __restrict__ ws_f) {
    int bidx = blockIdx.x;
    int dir = (bidx >= BLOCKS_PER_DIR) ? 1 : 0;
    int node = (bidx - dir * BLOCKS_PER_DIR) * GROUPS_PER_BLOCK + (threadIdx.x >> 3);
    if (node >= N_NODES) return;
    int lane = threadIdx.x & 7;
    const int* no = ws_i + WS_NOFF;
    const int2* pair = (const int2*)(ws_i + (dir == 0 ? WS_PAIR0 : WS_PAIR1));
    float* rdeg = ws_f + (dir == 0 ? WS_RDEG_IN : WS_RDEG_OUT);
    int sub = dir * N_EDGES;

    int D = dir * N_NODES + node;
    int start = no[D] - sub, end = no[D + 1] - sub;
    float s = 0.f;
    for (int p = start + lane; p < end; p += 8) s += __int_as_float(pair[p].y);
    s += __shfl_down(s, 4, 8);
    s += __shfl_down(s, 2, 8);
    s += __shfl_down(s, 1, 8);
    if (lane == 0) rdeg[node] = (s != 0.f) ? (1.f / s) : 0.f;
}

// 6. register-accumulating gather: 8 lanes/node, coef = w * rdeg[src]
__global__ __launch_bounds__(256) void gather_kernel(
    const float4* __restrict__ x4, const int* __restrict__ node_offs, int dir,
    const int2* __restrict__ pair, const float* __restrict__ rdeg,
    float4* __restrict__ outp) {
    int node = blockIdx.x * GROUPS_PER_BLOCK + (threadIdx.x >> 3);
    if (node >= N_NODES) return;
    int lane = threadIdx.x & 7;
    int sub = dir * N_EDGES;

    int D = dir * N_NODES + node;
    int p = node_offs[D] - sub;
    int end = node_offs[D + 1] - sub;
    float4 acc = make_float4(0.f, 0.f, 0.f, 0.f);
    for (; p + 1 < end; p += 2) {
        int2 e0 = pair[p], e1 = pair[p + 1];
        float c0 = __int_as_float(e0.y) * rdeg[e0.x];
        float c1 = __int_as_float(e1.y) * rdeg[e1.x];
        float4 a = x4[e0.x * 8 + lane];
        float4 bb = x4[e1.x * 8 + lane];
        acc.x += c0 * a.x + c1 * bb.x;
        acc.y += c0 * a.y + c1 * bb.y;
        acc.z += c0 * a.z + c1 * bb.z;
        acc.w += c0 * a.w + c1 * bb.w;
    }
    if (p < end) {
        int2 e0 = pair[p];
        float c0 = __int_as_float(e0.y) * rdeg[e0.x];
        float4 a = x4[e0.x * 8 + lane];
        acc.x += c0 * a.x;
        acc.y += c0 * a.y;
        acc.z += c0 * a.z;
        acc.w += c0 * a.w;
    }
    outp[node * 8 + lane] = acc;
}

// 7. Fused dense epilogue (unchanged; off the top-5 since round 4)
#define DN_GROUP 64
#define DN_BLOCKS ((N_NODES + DN_GROUP - 1) / DN_GROUP)  // 782
#define WT_STRIDE 100
__global__ __launch_bounds__(256) void dense_kernel(
    const float4* __restrict__ x4,
    const float4* __restrict__ txo4, const float4* __restrict__ txi4,
    const float* __restrict__ Wz, const float* __restrict__ bz,
    const float* __restrict__ Wh, const float* __restrict__ bh,
    const float* __restrict__ Wlin, const float* __restrict__ blin,
    float* __restrict__ out) {
    __shared__ float s_wzT[64 * WT_STRIDE];
    __shared__ float s_whT[64 * WT_STRIDE];
    __shared__ float s_in[DN_GROUP * 96];

    int tid = threadIdx.x;
    int o = tid & 63, w = tid >> 6;
    float bzo = bz[o], bho = bh[o], wlo = Wlin[o], bl = blin[0];

    for (int idx = tid; idx < 96 * 64; idx += 256) {
        int k = idx >> 6, oo = idx & 63;
        int slab = k >> 5, c = k & 31;
        float wz, wh;
        if (slab == 0) {
            wz = Wz[c * 64 + oo] + Wz[(2 * 96 + c) * 64 + oo];
            wh = Wh[c * 64 + oo] + Wh[(2 * 96 + c) * 64 + oo];
        } else if (slab == 1) {
            wz = Wz[(96 + c) * 64 + oo];
            wh = Wh[(96 + c) * 64 + oo];
        } else {
            wz = Wz[(3 * 96 + c) * 64 + oo];
            wh = Wh[(3 * 96 + c) * 64 + oo];
        }
        s_wzT[oo * WT_STRIDE + k] = wz;
        s_whT[oo * WT_STRIDE + k] = wh;
    }

    int node0 = blockIdx.x * DN_GROUP;
    for (int idx = tid; idx < DN_GROUP * 24; idx += 256) {
        int nl = idx / 24, q = idx - nl * 24;
        int node = node0 + nl;
        float4 v = make_float4(0.f, 0.f, 0.f, 0.f);
        if (node < N_NODES) {
            if (q < 8)       v = x4[node * 8 + q];
            else if (q < 16) v = txo4[node * 8 + (q - 8)];
            else             v = txi4[node * 8 + (q - 16)];
        }
        *(float4*)&s_in[nl * 96 + q * 4] = v;
    }
    __syncthreads();

    float accz[16], acch[16];
#pragma unroll
    for (int n = 0; n < 16; ++n) { accz[n] = bzo; acch[n] = bho; }
    const float* wzp = &s_wzT[o * WT_STRIDE];
    const float* whp = &s_whT[o * WT_STRIDE];
    const float* inp = &s_in[w * 16 * 96];

    for (int kq = 0; kq < 24; ++kq) {
        float4 wz = *(const float4*)&wzp[kq * 4];
        float4 wh = *(const float4*)&whp[kq * 4];
#pragma unroll
        for (int n = 0; n < 16; ++n) {
            float4 xk = *(const float4*)&inp[n * 96 + kq * 4];
            accz[n] += xk.x * wz.x + xk.y * wz.y + xk.z * wz.z + xk.w * wz.w;
            acch[n] += xk.x * wh.x + xk.y * wh.y + xk.z * wh.z + xk.w * wh.w;
        }
    }

#pragma unroll
    for (int n = 0; n < 16; ++n) {
        float z = 1.f / (1.f + __expf(-accz[n]));
        float ht = 1.f - 2.f / (__expf(2.f * acch[n]) + 1.f);
        float rr = fmaxf((1.f - z) * ht, 0.f) * wlo;
#pragma unroll
        for (int off = 32; off > 0; off >>= 1)
            rr += __shfl_down(rr, off, 64);
        if (o == 0) {
            int node = node0 + w * 16 + n;
            if (node < N_NODES) out[node] = rr + bl;
        }
    }
}

extern "C" void kernel_launch(void* const* d_in, const int* in_sizes, int n_in,
                              void* d_out, int out_size, void* d_ws, size_t ws_size,
                              hipStream_t stream) {
    const float* x = (const float*)d_in[0];
    const int* ei = (const int*)d_in[1];
    const float* ew = (const float*)d_in[2];
    const float* Wz = (const float*)d_in[3];
    const float* bz = (const float*)d_in[4];
    // d_in[5]=Wr, d_in[6]=br dead: H0==0 makes the reset gate a no-op
    const float* Wh = (const float*)d_in[7];
    const float* bh = (const float*)d_in[8];
    const float* Wlin = (const float*)d_in[9];
    const float* blin = (const float*)d_in[10];
    float* out = (float*)d_out;
    float* wf = (float*)d_ws;
    int* wi = (int*)d_ws;

    int2* binned = (int2*)(wi + WS_BINNED);
    int2* pair0 = (int2*)(wi + WS_PAIR0);
    int2* pair1 = (int2*)(wi + WS_PAIR1);

    // 1. coarse per-chunk histograms (writes every cntG entry -> no zero pass)
    hist_kernel<<<NCHK, 512, 0, stream>>>(ei, wi + WS_CNTG);
    // 2. exclusive scan of the (dir,bin,chunk) count matrix
    scan_partial_kernel<<<SCAN_BLOCKS, 256, 0, stream>>>(
        (const int4*)(wi + WS_CNTG), wi + WS_BLKSUM, CNTG_N4);
    scan_blocksum_kernel<<<1, 256, 0, stream>>>(wi + WS_BLKSUM, SCAN_BLOCKS);
    scan_final_kernel<<<SCAN_BLOCKS, 256, 0, stream>>>(
        (int4*)(wi + WS_CNTG), wi + WS_BLKSUM, CNTG_N4);
    // 3/4. dir0 (group by col): coarse partition -> per-bin exact sort
    partition_kernel<<<NCHK, 512, 0, stream>>>(ei, ew, wi + WS_CNTG, binned, 0);
    binsort_kernel<<<NBIN, 512, 0, stream>>>(wi + WS_CNTG, binned, pair0, wi + WS_NOFF, 0);
    //      dir1 (group by row): reuses the binned staging buffer
    partition_kernel<<<NCHK, 512, 0, stream>>>(ei, ew, wi + WS_CNTG, binned, 1);
    binsort_kernel<<<NBIN, 512, 0, stream>>>(wi + WS_CNTG, binned, pair1, wi + WS_NOFF, 1);
    // 5. degrees from sorted lists -> reciprocals
    deg_kernel<<<2 * BLOCKS_PER_DIR, 256, 0, stream>>>(wi, wf);
    // 6a. gather dir0: col lists x rdeg_out -> Tx_o (overwrites dead binned region)
    gather_kernel<<<BLOCKS_PER_DIR, 256, 0, stream>>>(
        (const float4*)x, wi + WS_NOFF, 0, pair0, wf + WS_RDEG_OUT,
        (float4*)(wf + WS_TXO));
    // 6b. gather dir1: row lists x rdeg_in -> Tx_i
    gather_kernel<<<BLOCKS_PER_DIR, 256, 0, stream>>>(
        (const float4*)x, wi + WS_NOFF, 1, pair1, wf + WS_RDEG_IN,
        (float4*)(wf + WS_TXI));
    // 7. fused dense epilogue
    dense_kernel<<<DN_BLOCKS, 256, 0, stream>>>(
        (const float4*)x, (const float4*)(wf + WS_TXO), (const float4*)(wf + WS_TXI),
        Wz, bz, Wh, bh, Wlin, blin, out);
}